// Round 1
// baseline (398.897 us; speedup 1.0000x reference)
//
#include <hip/hip_runtime.h>
#include <hip/hip_bf16.h>

// Problem constants (from reference setup_inputs)
#define BB 4
#define CIN 64
#define HH 160
#define WW 160
#define COUT 64
#define OFFC 18          // 2*K2
#define K2 9
#define HWD (HH * WW)    // 25600
#define OUT_ELEMS (BB * COUT * HWD)   // 6,553,600
#define EPSBN 1e-5f

// ---------------------------------------------------------------------------
// prep: transpose weights to [c][k][o] (o contiguous -> scalar loads in the
// hot loops), and zero the BN double accumulators.
// ws layout (floats): wct[64*9*64]=36864, wot[64*9*18]=10368, then 128 doubles
// ---------------------------------------------------------------------------
__global__ void prep_kernel(const float* __restrict__ cw,
                            const float* __restrict__ ow,
                            float* __restrict__ wct,
                            float* __restrict__ wot,
                            double* __restrict__ sums) {
  int i = blockIdx.x * 256 + threadIdx.x;
  if (i < 36864) {                       // conv_w [o][c][k] -> wct[(c*9+k)*64+o]
    int o = i / 576, r = i % 576, c = r / 9, k = r % 9;
    wct[(c * 9 + k) * 64 + o] = cw[i];
  }
  if (i < 10368) {                       // offset_w [o][c][k] -> wot[(c*9+k)*18+o]
    int o = i / 576, r = i % 576, c = r / 9, k = r % 9;
    wot[(c * 9 + k) * 18 + o] = ow[i];
  }
  if (i < 128) sums[i] = 0.0;
}

// ---------------------------------------------------------------------------
// offset conv: 3x3, pad 1, 64 -> 18 channels, clamp to [-1,1].
// One block = 16x16 pixel tile of one batch image. LDS-staged 18x18 patch,
// 16-channel chunks. Weights via uniform (scalar) loads from wot.
// ---------------------------------------------------------------------------
__global__ __launch_bounds__(256) void offconv_kernel(
    const float* __restrict__ d, const float* __restrict__ wot,
    float* __restrict__ off_out) {
  const int b = blockIdx.z;
  const int tx0 = blockIdx.x * 16, ty0 = blockIdx.y * 16;
  const int tx = threadIdx.x & 15, ty = threadIdx.x >> 4;

  __shared__ float patch[16][324];   // 16 ch x 18x18

  float acc[18];
#pragma unroll
  for (int o = 0; o < 18; ++o) acc[o] = 0.f;

  for (int cb = 0; cb < 64; cb += 16) {
    __syncthreads();
    for (int l = threadIdx.x; l < 16 * 324; l += 256) {
      int c = l / 324, rc = l % 324, r = rc / 18, col = rc % 18;
      int gy = ty0 - 1 + r, gx = tx0 - 1 + col;
      float v = 0.f;
      if (gy >= 0 && gy < HH && gx >= 0 && gx < WW)
        v = d[((b * 64 + cb + c) * HH + gy) * WW + gx];
      patch[c][rc] = v;
    }
    __syncthreads();
    for (int c = 0; c < 16; ++c) {
#pragma unroll
      for (int k = 0; k < 9; ++k) {
        const int kh = k / 3, kw = k % 3;
        float v = patch[c][(ty + kh) * 18 + tx + kw];
        const float* wp = wot + ((cb + c) * 9 + k) * 18;  // uniform -> s_load
#pragma unroll
        for (int o = 0; o < 18; ++o) acc[o] = fmaf(v, wp[o], acc[o]);
      }
    }
  }
  const int h = ty0 + ty, w = tx0 + tx;
#pragma unroll
  for (int o = 0; o < 18; ++o) {
    float v = fminf(1.f, fmaxf(-1.f, acc[o]));
    off_out[((b * 18 + o) * HH + h) * WW + w] = v;
  }
}

// ---------------------------------------------------------------------------
// deformable conv main. One block = 16x16 tile of one batch. Because offsets
// are clamped to [-1,1], all bilinear corners for the tile live in a 21x21
// patch per channel (zero-padded => reference's zero-pad gather semantics).
// Per (c,tap): 4 LDS reads + interp + 64 FMAs with scalar weights.
// Writes pre-BN conv output to `out` (d_out region, normalized in place later).
// ---------------------------------------------------------------------------
__global__ __launch_bounds__(256) void dconv_kernel(
    const float* __restrict__ x, const float* __restrict__ offs,
    const float* __restrict__ wct, float* __restrict__ out) {
  const int b = blockIdx.z;
  const int tx0 = blockIdx.x * 16, ty0 = blockIdx.y * 16;
  const int tx = threadIdx.x & 15, ty = threadIdx.x >> 4;
  const int h = ty0 + ty, w = tx0 + tx;

  // Per-tap precompute: patch-relative corner base + 4 bilinear weights.
  int bse[9];
  float w00[9], w01[9], w10[9], w11[9];
#pragma unroll
  for (int k = 0; k < 9; ++k) {
    const int kh = k / 3, kw = k % 3;
    float dy = offs[((b * 18 + 2 * k) * HH + h) * WW + w];
    float dx = offs[((b * 18 + 2 * k + 1) * HH + h) * WW + w];
    float py = (float)(h - 1 + kh) + dy;
    float px = (float)(w - 1 + kw) + dx;
    float y0f = floorf(py), x0f = floorf(px);
    float wy = py - y0f, wx = px - x0f;
    int ry = (int)y0f - (ty0 - 2);   // in [0,20] by clamp guarantee
    int rx = (int)x0f - (tx0 - 2);
    bse[k] = ry * 21 + rx;
    w00[k] = (1.f - wy) * (1.f - wx);
    w01[k] = (1.f - wy) * wx;
    w10[k] = wy * (1.f - wx);
    w11[k] = wy * wx;
  }

  __shared__ float patch[16 * 441];  // 16 ch x 21x21

  float acc[64];
#pragma unroll
  for (int o = 0; o < 64; ++o) acc[o] = 0.f;

  for (int cb = 0; cb < 64; cb += 16) {
    __syncthreads();
    for (int l = threadIdx.x; l < 16 * 441; l += 256) {
      int c = l / 441, rc = l % 441, r = rc / 21, col = rc % 21;
      int gy = ty0 - 2 + r, gx = tx0 - 2 + col;
      float v = 0.f;
      if (gy >= 0 && gy < HH && gx >= 0 && gx < WW)
        v = x[((b * 64 + cb + c) * HH + gy) * WW + gx];
      patch[l] = v;
    }
    __syncthreads();
    for (int c = 0; c < 16; ++c) {
      const float* pc = patch + c * 441;
#pragma unroll
      for (int k = 0; k < 9; ++k) {
        const int bs = bse[k];
        float v00 = pc[bs], v01 = pc[bs + 1];
        float v10 = pc[bs + 21], v11 = pc[bs + 22];
        float val = w00[k] * v00 + w01[k] * v01 + w10[k] * v10 + w11[k] * v11;
        const float* wp = wct + ((cb + c) * 9 + k) * 64;  // uniform -> s_load
#pragma unroll
        for (int o = 0; o < 64; ++o) acc[o] = fmaf(val, wp[o], acc[o]);
      }
    }
  }
#pragma unroll
  for (int o = 0; o < 64; ++o)
    out[((b * 64 + o) * HH + h) * WW + w] = acc[o];
}

// ---------------------------------------------------------------------------
// BN stats: one block per (b, o) slice (25600 contiguous floats), double
// accumulate, LDS reduce, 2 f64 atomics per block into ws sums.
// ---------------------------------------------------------------------------
__global__ __launch_bounds__(256) void bnstats_kernel(
    const float* __restrict__ out, double* __restrict__ sums) {
  const int bo = blockIdx.x;           // b*64+o
  const int o = bo & 63;
  const float4* p = (const float4*)(out + bo * HWD);
  double s = 0.0, s2 = 0.0;
  for (int i = threadIdx.x; i < HWD / 4; i += 256) {
    float4 v = p[i];
    s += (double)v.x + (double)v.y + (double)v.z + (double)v.w;
    s2 += (double)v.x * v.x + (double)v.y * v.y +
          (double)v.z * v.z + (double)v.w * v.w;
  }
  __shared__ double sh[2][256];
  sh[0][threadIdx.x] = s;
  sh[1][threadIdx.x] = s2;
  __syncthreads();
  for (int t = 128; t > 0; t >>= 1) {
    if (threadIdx.x < t) {
      sh[0][threadIdx.x] += sh[0][threadIdx.x + t];
      sh[1][threadIdx.x] += sh[1][threadIdx.x + t];
    }
    __syncthreads();
  }
  if (threadIdx.x == 0) {
    atomicAdd(&sums[o], sh[0][0]);
    atomicAdd(&sums[64 + o], sh[1][0]);
  }
}

// ---------------------------------------------------------------------------
// BN apply + ReLU, in place on d_out's conv region (float4 vectorized).
// ---------------------------------------------------------------------------
__global__ __launch_bounds__(256) void bnapply_kernel(
    float* __restrict__ out, const double* __restrict__ sums,
    const float* __restrict__ gamma, const float* __restrict__ beta) {
  const int i = blockIdx.x * 256 + threadIdx.x;  // over OUT_ELEMS/4
  if (i >= OUT_ELEMS / 4) return;
  const int o = (i / (HWD / 4)) & 63;
  const float n_inv = 1.0f / (float)(BB * HWD);
  float mean = (float)sums[o] * n_inv;
  float var = (float)sums[64 + o] * n_inv - mean * mean;
  float inv = gamma[o] * rsqrtf(var + EPSBN);
  float bt = beta[o];
  float4 v = ((float4*)out)[i];
  v.x = fmaxf(0.f, (v.x - mean) * inv + bt);
  v.y = fmaxf(0.f, (v.y - mean) * inv + bt);
  v.z = fmaxf(0.f, (v.z - mean) * inv + bt);
  v.w = fmaxf(0.f, (v.w - mean) * inv + bt);
  ((float4*)out)[i] = v;
}

extern "C" void kernel_launch(void* const* d_in, const int* in_sizes, int n_in,
                              void* d_out, int out_size, void* d_ws, size_t ws_size,
                              hipStream_t stream) {
  const float* x = (const float*)d_in[0];      // [4,64,160,160]
  const float* d = (const float*)d_in[1];      // [4,64,160,160]
  const float* ow = (const float*)d_in[2];     // [18,64,3,3]
  const float* cw = (const float*)d_in[3];     // [64,64,3,3]
  const float* gamma = (const float*)d_in[4];  // [64]
  const float* beta = (const float*)d_in[5];   // [64]

  float* out = (float*)d_out;                  // conv/BN output, 6,553,600 f32
  float* off_out = out + OUT_ELEMS;            // clamped offsets, 1,843,200 f32

  // workspace: wct (36864 f) | wot (10368 f) | sums (128 doubles, 8B-aligned)
  float* wct = (float*)d_ws;
  float* wot = wct + 36864;
  double* sums = (double*)(wot + 10368);       // byte offset 188928, %8==0

  prep_kernel<<<144, 256, 0, stream>>>(cw, ow, wct, wot, sums);

  dim3 tiles(WW / 16, HH / 16, BB);            // 10x10x4
  offconv_kernel<<<tiles, 256, 0, stream>>>(d, wot, off_out);
  dconv_kernel<<<tiles, 256, 0, stream>>>(x, off_out, wct, out);

  bnstats_kernel<<<BB * COUT, 256, 0, stream>>>(out, sums);
  bnapply_kernel<<<(OUT_ELEMS / 4 + 255) / 256, 256, 0, stream>>>(
      out, sums, gamma, beta);
}